// Round 3
// baseline (1348.049 us; speedup 1.0000x reference)
//
#include <hip/hip_runtime.h>
#include <math.h>

// AxialChannelAttention on MI355X, fp32.
// Decomposition:
//   axial = U[b,r,w] + V[b,r,h]  (separable pooling through linear conv1)
//   lrelu(s) = 0.505*s + 0.495*|s|
//   g_avg+g_max = PS[b,c,w] + QS[b,c,h] + 0.495 * sum_r w2[c,r]*m[b,r,h,w]
//   m = |U_a+V_a| + |U_m+V_m|   (single per-pixel matvec for BOTH branches)

#define B_  16
#define C_  256
#define CR_ 64
#define H_  128
#define W_  128
#define NEGINF -3.402823466e38f

constexpr size_t SSTRIDE  = (size_t)B_ * C_ * W_;   // 524288 floats per stat array
constexpr size_t USTRIDE  = (size_t)B_ * CR_ * W_;  // 131072 floats per U array
constexpr size_t PQSTRIDE = (size_t)B_ * C_ * W_;   // 524288 floats per PS/QS

// ---------------- Kernel 1: axial pooling (sum+max over H and over W) ---------
// Block per (b,c) plane, 256 threads. Thread: cols wg*4..+3 (float4), rows
// rg+8k. Column stats vertical in regs (no shuffles); row stats via 5-step
// half-wave (32-lane) shuffle per row. LDS only for small partials (9 KB).
__global__ __launch_bounds__(256) void k1_pool(const float* __restrict__ x,
                                               float* __restrict__ S) {
    const int c = blockIdx.x, b = blockIdx.y;
    const int tid = threadIdx.x;
    const int wg = tid & 31;   // col group: cols wg*4..wg*4+3
    const int rg = tid >> 5;   // 0..7: rows rg + 8k
    const float* xp = x + (size_t)(b * C_ + c) * (H_ * W_);

    __shared__ float rs_l[H_], rm_l[H_];
    __shared__ float cps[8][W_], cpm[8][W_];

    float cs0 = 0.f, cs1 = 0.f, cs2 = 0.f, cs3 = 0.f;
    float cm0 = NEGINF, cm1 = NEGINF, cm2 = NEGINF, cm3 = NEGINF;

#pragma unroll 4
    for (int k = 0; k < 16; ++k) {
        const int h = rg + 8 * k;
        const float4 v = *reinterpret_cast<const float4*>(xp + h * W_ + wg * 4);
        cs0 += v.x; cs1 += v.y; cs2 += v.z; cs3 += v.w;
        cm0 = fmaxf(cm0, v.x); cm1 = fmaxf(cm1, v.y);
        cm2 = fmaxf(cm2, v.z); cm3 = fmaxf(cm3, v.w);
        float rs = (v.x + v.y) + (v.z + v.w);
        float rm = fmaxf(fmaxf(v.x, v.y), fmaxf(v.z, v.w));
#pragma unroll
        for (int m = 1; m < 32; m <<= 1) {   // stays within each 32-lane half
            rs += __shfl_xor(rs, m);
            rm = fmaxf(rm, __shfl_xor(rm, m));
        }
        if (wg == 0) { rs_l[h] = rs; rm_l[h] = rm; }
    }
    *reinterpret_cast<float4*>(&cps[rg][wg * 4]) = make_float4(cs0, cs1, cs2, cs3);
    *reinterpret_cast<float4*>(&cpm[rg][wg * 4]) = make_float4(cm0, cm1, cm2, cm3);
    __syncthreads();

    if (tid < 128) {
        float ssum = 0.f, smax = NEGINF;
#pragma unroll
        for (int g = 0; g < 8; ++g) {
            ssum += cps[g][tid];
            smax = fmaxf(smax, cpm[g][tid]);
        }
        const size_t o = (size_t)(b * C_ + c) * W_ + tid;
        S[0 * SSTRIDE + o] = ssum * (1.0f / 128.0f);      // avg_h[b,c,w]
        S[1 * SSTRIDE + o] = smax;                        // max_h[b,c,w]
        S[2 * SSTRIDE + o] = rs_l[tid] * (1.0f / 128.0f); // avg_w[b,c,h]
        S[3 * SSTRIDE + o] = rm_l[tid];                   // max_w[b,c,h]
    }
}

// ---------------- Kernel 2a: U[src][b][r][t] = sum_c w1[r,c] * S[src][b][c][t]
__global__ __launch_bounds__(128) void k2a_u(const float* __restrict__ S,
                                             const float* __restrict__ w1,
                                             float* __restrict__ U) {
    const int t   = threadIdx.x;   // 0..127 (w or h)
    const int rq  = blockIdx.x;    // 0..15 -> 4 r's per block
    const int src = blockIdx.y;    // 0..3
    const int b   = blockIdx.z;
    const float* in = S + ((size_t)(src * B_ + b) * C_) * W_;

    float acc[4];
#pragma unroll
    for (int i = 0; i < 4; ++i) acc[i] = 0.f;

#pragma unroll 8
    for (int c = 0; c < C_; ++c) {
        const float xv = in[c * W_ + t];
#pragma unroll
        for (int i = 0; i < 4; ++i)
            acc[i] = fmaf(w1[(rq * 4 + i) * C_ + c], xv, acc[i]);  // uniform -> s_load
    }
    float* o = U + ((size_t)(src * B_ + b) * CR_ + rq * 4) * W_;
#pragma unroll
    for (int i = 0; i < 4; ++i) o[i * W_ + t] = acc[i];
}

// ---------------- Kernel 2b: PS/QS (linear part of lrelu through conv2) ------
// PS[b,c,w] = 0.505 * sum_r w2[c,r]*(U_a[b,r,w]+U_m[b,r,w]);  QS analog with V.
__global__ __launch_bounds__(128) void k2b_pq(const float* __restrict__ U,
                                              const float* __restrict__ w2,
                                              float* __restrict__ PQ) {
    const int t  = threadIdx.x;  // w or h
    const int cq = blockIdx.x;   // 0..31 -> 8 c's per block
    const int pq = blockIdx.y;   // 0 = PS (from U_a,U_m), 1 = QS (from V_a,V_m)
    const int b  = blockIdx.z;
    const float* u0 = U + ((size_t)((pq * 2 + 0) * B_ + b) * CR_) * W_;
    const float* u1 = U + ((size_t)((pq * 2 + 1) * B_ + b) * CR_) * W_;

    float acc[8];
#pragma unroll
    for (int i = 0; i < 8; ++i) acc[i] = 0.f;

#pragma unroll 8
    for (int r = 0; r < CR_; ++r) {
        const float sv = u0[r * W_ + t] + u1[r * W_ + t];
#pragma unroll
        for (int i = 0; i < 8; ++i)
            acc[i] = fmaf(w2[(cq * 8 + i) * CR_ + r], sv, acc[i]);  // uniform -> s_load
    }
    float* o = PQ + ((size_t)(pq * B_ + b) * C_ + cq * 8) * W_;
#pragma unroll
    for (int i = 0; i < 8; ++i) o[i * W_ + t] = 0.505f * acc[i];
}

// ---------------- Kernel 3: fused abs-matvec + sigmoid + scale ---------------
// Block per (b,h), 512 threads (8 waves). m stored TRANSPOSED sm[w][r] (+4 pad
// so each thread's 8 consecutive r are two aligned ds_read_b128 at minimum
// bank aliasing). Wave owns a 32-c block (uniform -> w2 via s_load_dwordx8);
// lane owns w pair (float2 global traffic).
__global__ __launch_bounds__(512) void k3_gate(const float* __restrict__ x,
                                               const float* __restrict__ U,
                                               const float* __restrict__ PQ,
                                               const float* __restrict__ w2,
                                               float* __restrict__ out) {
    const int h = blockIdx.x, b = blockIdx.y;
    const int tid = threadIdx.x;

    __shared__ float sm[W_][CR_ + 4];  // 34 KB, transposed: sm[w][r]

    const float* Ua = U + (size_t)(0 * B_ + b) * CR_ * W_;
    const float* Um = U + (size_t)(1 * B_ + b) * CR_ * W_;
    const float* Va = U + (size_t)(2 * B_ + b) * CR_ * W_;
    const float* Vm = U + (size_t)(3 * B_ + b) * CR_ * W_;

    for (int idx = tid; idx < CR_ * W_; idx += 512) {
        const int r = idx >> 7, w = idx & 127;       // lanes: consecutive w (coalesced)
        const float va = Va[r * W_ + h];             // uniform
        const float vm = Vm[r * W_ + h];
        sm[w][r] = fabsf(Ua[r * W_ + w] + va) + fabsf(Um[r * W_ + w] + vm);
    }
    __syncthreads();

    const int lane = tid & 63;
    const int w0 = lane * 2, w1 = w0 + 1;
    const int cbase = __builtin_amdgcn_readfirstlane(tid >> 6) * 32;  // wave-uniform

    const float* PQ0 = PQ + (size_t)b * C_ * W_;               // PS[b][c][w]
    const float* PQ1 = PQ + PQSTRIDE + (size_t)b * C_ * W_;    // QS[b][c][h]

    float2 acc[32];
#pragma unroll
    for (int i = 0; i < 32; ++i) acc[i] = make_float2(0.f, 0.f);

    for (int r8 = 0; r8 < 8; ++r8) {   // r-tile of 8
        const float4 a0 = *reinterpret_cast<const float4*>(&sm[w0][r8 * 8]);
        const float4 a1 = *reinterpret_cast<const float4*>(&sm[w0][r8 * 8 + 4]);
        const float4 b0 = *reinterpret_cast<const float4*>(&sm[w1][r8 * 8]);
        const float4 b1 = *reinterpret_cast<const float4*>(&sm[w1][r8 * 8 + 4]);
#pragma unroll
        for (int i = 0; i < 32; ++i) {
            const float* wr = &w2[(size_t)(cbase + i) * CR_ + r8 * 8];  // 8 contiguous: s_load_dwordx8
            acc[i].x = fmaf(wr[0], a0.x, acc[i].x);
            acc[i].x = fmaf(wr[1], a0.y, acc[i].x);
            acc[i].x = fmaf(wr[2], a0.z, acc[i].x);
            acc[i].x = fmaf(wr[3], a0.w, acc[i].x);
            acc[i].x = fmaf(wr[4], a1.x, acc[i].x);
            acc[i].x = fmaf(wr[5], a1.y, acc[i].x);
            acc[i].x = fmaf(wr[6], a1.z, acc[i].x);
            acc[i].x = fmaf(wr[7], a1.w, acc[i].x);
            acc[i].y = fmaf(wr[0], b0.x, acc[i].y);
            acc[i].y = fmaf(wr[1], b0.y, acc[i].y);
            acc[i].y = fmaf(wr[2], b0.z, acc[i].y);
            acc[i].y = fmaf(wr[3], b0.w, acc[i].y);
            acc[i].y = fmaf(wr[4], b1.x, acc[i].y);
            acc[i].y = fmaf(wr[5], b1.y, acc[i].y);
            acc[i].y = fmaf(wr[6], b1.z, acc[i].y);
            acc[i].y = fmaf(wr[7], b1.w, acc[i].y);
        }
    }

#pragma unroll 4
    for (int i = 0; i < 32; ++i) {
        const int c = cbase + i;
        const float q1 = PQ1[(size_t)c * W_ + h];  // uniform
        const float2 p0 = *reinterpret_cast<const float2*>(&PQ0[(size_t)c * W_ + w0]);
        const float zx = p0.x + q1 + 0.495f * acc[i].x;
        const float zy = p0.y + q1 + 0.495f * acc[i].y;
        const float sgx = __builtin_amdgcn_rcpf(1.0f + __expf(-zx));
        const float sgy = __builtin_amdgcn_rcpf(1.0f + __expf(-zy));
        const size_t xo = ((size_t)(b * C_ + c) * H_ + h) * W_ + w0;
        const float2 xv = *reinterpret_cast<const float2*>(&x[xo]);
        float2 ov;
        ov.x = xv.x * (1.0f + sgx);
        ov.y = xv.y * (1.0f + sgy);
        *reinterpret_cast<float2*>(&out[xo]) = ov;
    }
}

extern "C" void kernel_launch(void* const* d_in, const int* in_sizes, int n_in,
                              void* d_out, int out_size, void* d_ws, size_t ws_size,
                              hipStream_t stream) {
    (void)in_sizes; (void)n_in; (void)out_size; (void)ws_size;
    const float* x  = (const float*)d_in[0];
    const float* w1 = (const float*)d_in[1];
    const float* w2 = (const float*)d_in[2];
    float* out = (float*)d_out;

    float* S  = (float*)d_ws;              // 4 * 524288 floats
    float* U  = S + 4 * SSTRIDE;           // 4 * 131072 floats
    float* PQ = U + 4 * USTRIDE;           // 2 * 524288 floats
    // total workspace: 3,670,016 floats = 14 MB

    k1_pool<<<dim3(C_, B_), 256, 0, stream>>>(x, S);
    k2a_u  <<<dim3(16, 4, B_), 128, 0, stream>>>(S, w1, U);
    k2b_pq <<<dim3(32, 2, B_), 128, 0, stream>>>(U, w2, PQ);
    k3_gate<<<dim3(H_, B_), 512, 0, stream>>>(x, U, PQ, w2, out);
}

// Round 4
// 676.384 us; speedup vs baseline: 1.9930x; 1.9930x over previous
//
#include <hip/hip_runtime.h>
#include <math.h>

// AxialChannelAttention on MI355X, fp32.
// Decomposition:
//   axial = U[b,r,w] + V[b,r,h]  (separable pooling through linear conv1)
//   lrelu(s) = 0.505*s + 0.495*|s|
//   g_avg+g_max = PS[b,c,w] + QS[b,c,h] + 0.495 * sum_r w2[c,r]*m[b,r,h,w]
//   m = |U_a+V_a| + |U_m+V_m|   (single per-pixel matvec for BOTH branches)
// Round-4 fix: k3 round-3 version spilled acc[32] to scratch (VGPR=36,
// 4 GB HBM traffic) because the partially-unrolled epilogue runtime-indexed
// the accumulator array. All acc-indexing loops are now fully unrolled.

#define B_  16
#define C_  256
#define CR_ 64
#define H_  128
#define W_  128
#define NEGINF -3.402823466e38f

constexpr size_t SSTRIDE  = (size_t)B_ * C_ * W_;   // 524288 floats per stat array
constexpr size_t USTRIDE  = (size_t)B_ * CR_ * W_;  // 131072 floats per U array
constexpr size_t PQSTRIDE = (size_t)B_ * C_ * W_;   // 524288 floats per PS/QS

// ---------------- Kernel 1: axial pooling (sum+max over H and over W) ---------
__global__ __launch_bounds__(256) void k1_pool(const float* __restrict__ x,
                                               float* __restrict__ S) {
    const int c = blockIdx.x, b = blockIdx.y;
    const int tid = threadIdx.x;
    const int wg = tid & 31;   // col group: cols wg*4..wg*4+3
    const int rg = tid >> 5;   // 0..7: rows rg + 8k
    const float* xp = x + (size_t)(b * C_ + c) * (H_ * W_);

    __shared__ float rs_l[H_], rm_l[H_];
    __shared__ float cps[8][W_], cpm[8][W_];

    float cs0 = 0.f, cs1 = 0.f, cs2 = 0.f, cs3 = 0.f;
    float cm0 = NEGINF, cm1 = NEGINF, cm2 = NEGINF, cm3 = NEGINF;

#pragma unroll 4
    for (int k = 0; k < 16; ++k) {
        const int h = rg + 8 * k;
        const float4 v = *reinterpret_cast<const float4*>(xp + h * W_ + wg * 4);
        cs0 += v.x; cs1 += v.y; cs2 += v.z; cs3 += v.w;
        cm0 = fmaxf(cm0, v.x); cm1 = fmaxf(cm1, v.y);
        cm2 = fmaxf(cm2, v.z); cm3 = fmaxf(cm3, v.w);
        float rs = (v.x + v.y) + (v.z + v.w);
        float rm = fmaxf(fmaxf(v.x, v.y), fmaxf(v.z, v.w));
#pragma unroll
        for (int m = 1; m < 32; m <<= 1) {   // stays within each 32-lane half
            rs += __shfl_xor(rs, m);
            rm = fmaxf(rm, __shfl_xor(rm, m));
        }
        if (wg == 0) { rs_l[h] = rs; rm_l[h] = rm; }
    }
    *reinterpret_cast<float4*>(&cps[rg][wg * 4]) = make_float4(cs0, cs1, cs2, cs3);
    *reinterpret_cast<float4*>(&cpm[rg][wg * 4]) = make_float4(cm0, cm1, cm2, cm3);
    __syncthreads();

    if (tid < 128) {
        float ssum = 0.f, smax = NEGINF;
#pragma unroll
        for (int g = 0; g < 8; ++g) {
            ssum += cps[g][tid];
            smax = fmaxf(smax, cpm[g][tid]);
        }
        const size_t o = (size_t)(b * C_ + c) * W_ + tid;
        S[0 * SSTRIDE + o] = ssum * (1.0f / 128.0f);      // avg_h[b,c,w]
        S[1 * SSTRIDE + o] = smax;                        // max_h[b,c,w]
        S[2 * SSTRIDE + o] = rs_l[tid] * (1.0f / 128.0f); // avg_w[b,c,h]
        S[3 * SSTRIDE + o] = rm_l[tid];                   // max_w[b,c,h]
    }
}

// ---------------- Kernel 2a: U[src][b][r][t] = sum_c w1[r,c] * S[src][b][c][t]
__global__ __launch_bounds__(128) void k2a_u(const float* __restrict__ S,
                                             const float* __restrict__ w1,
                                             float* __restrict__ U) {
    const int t   = threadIdx.x;   // 0..127 (w or h)
    const int rq  = blockIdx.x;    // 0..15 -> 4 r's per block
    const int src = blockIdx.y;    // 0..3
    const int b   = blockIdx.z;
    const float* in = S + ((size_t)(src * B_ + b) * C_) * W_;

    float acc[4];
#pragma unroll
    for (int i = 0; i < 4; ++i) acc[i] = 0.f;

#pragma unroll 8
    for (int c = 0; c < C_; ++c) {
        const float xv = in[c * W_ + t];
#pragma unroll
        for (int i = 0; i < 4; ++i)
            acc[i] = fmaf(w1[(rq * 4 + i) * C_ + c], xv, acc[i]);  // uniform -> s_load
    }
    float* o = U + ((size_t)(src * B_ + b) * CR_ + rq * 4) * W_;
#pragma unroll
    for (int i = 0; i < 4; ++i) o[i * W_ + t] = acc[i];
}

// ---------------- Kernel 2b: PS/QS (linear part of lrelu through conv2) ------
__global__ __launch_bounds__(128) void k2b_pq(const float* __restrict__ U,
                                              const float* __restrict__ w2,
                                              float* __restrict__ PQ) {
    const int t  = threadIdx.x;  // w or h
    const int cq = blockIdx.x;   // 0..31 -> 8 c's per block
    const int pq = blockIdx.y;   // 0 = PS (from U_a,U_m), 1 = QS (from V_a,V_m)
    const int b  = blockIdx.z;
    const float* u0 = U + ((size_t)((pq * 2 + 0) * B_ + b) * CR_) * W_;
    const float* u1 = U + ((size_t)((pq * 2 + 1) * B_ + b) * CR_) * W_;

    float acc[8];
#pragma unroll
    for (int i = 0; i < 8; ++i) acc[i] = 0.f;

#pragma unroll 8
    for (int r = 0; r < CR_; ++r) {
        const float sv = u0[r * W_ + t] + u1[r * W_ + t];
#pragma unroll
        for (int i = 0; i < 8; ++i)
            acc[i] = fmaf(w2[(cq * 8 + i) * CR_ + r], sv, acc[i]);  // uniform -> s_load
    }
    float* o = PQ + ((size_t)(pq * B_ + b) * C_ + cq * 8) * W_;
#pragma unroll
    for (int i = 0; i < 8; ++i) o[i * W_ + t] = 0.505f * acc[i];
}

// ---------------- Kernel 3: fused abs-matvec + sigmoid + scale ---------------
// Block per (b,h), 512 threads (8 waves). sm transposed [w][r] with +4 pad:
// rows 16B-aligned (ds_read_b128) and start-bank (4*lane mod 32) spread ->
// conflict-free at the b128 minimum. Lane owns w in {lane, lane+64}; wave owns
// 16 c per pass, 2 passes. EVERY loop indexing ax/ay is fully unrolled so the
// accumulators stay in VGPRs (round-3 scratch-spill fix).
__global__ __launch_bounds__(512) void k3_gate(const float* __restrict__ x,
                                               const float* __restrict__ U,
                                               const float* __restrict__ PQ,
                                               const float* __restrict__ w2,
                                               float* __restrict__ out) {
    const int h = blockIdx.x, b = blockIdx.y;
    const int tid = threadIdx.x;

    __shared__ float sm[W_][CR_ + 4];  // 34816 B

    const float* Ua = U + (size_t)(0 * B_ + b) * CR_ * W_;
    const float* Um = U + (size_t)(1 * B_ + b) * CR_ * W_;
    const float* Va = U + (size_t)(2 * B_ + b) * CR_ * W_;
    const float* Vm = U + (size_t)(3 * B_ + b) * CR_ * W_;

    for (int idx = tid; idx < CR_ * W_; idx += 512) {
        const int r = idx >> 7, w = idx & 127;       // lanes: consecutive w (coalesced)
        const float va = Va[r * W_ + h];             // wave-uniform
        const float vm = Vm[r * W_ + h];
        sm[w][r] = fabsf(Ua[r * W_ + w] + va) + fabsf(Um[r * W_ + w] + vm);
    }
    __syncthreads();

    const int lane = tid & 63;
    const int w0 = lane, w1 = lane + 64;
    const int wid = __builtin_amdgcn_readfirstlane(tid >> 6);  // 0..7, SGPR

    const float* PQ0 = PQ + (size_t)b * C_ * W_;               // PS[b][c][w]
    const float* PQ1 = PQ + PQSTRIDE + (size_t)b * C_ * W_;    // QS[b][c][h]

    for (int pass = 0; pass < 2; ++pass) {
        const int cbase = pass * 128 + wid * 16;   // wave-uniform

        float ax[16], ay[16];
#pragma unroll
        for (int i = 0; i < 16; ++i) { ax[i] = 0.f; ay[i] = 0.f; }

#pragma unroll 2
        for (int r8 = 0; r8 < 8; ++r8) {           // rolled K-loop: acc idx static
            const float4 a0 = *reinterpret_cast<const float4*>(&sm[w0][r8 * 8]);
            const float4 a1 = *reinterpret_cast<const float4*>(&sm[w0][r8 * 8 + 4]);
            const float4 c0 = *reinterpret_cast<const float4*>(&sm[w1][r8 * 8]);
            const float4 c1 = *reinterpret_cast<const float4*>(&sm[w1][r8 * 8 + 4]);
#pragma unroll
            for (int i = 0; i < 16; ++i) {
                const float* wr = &w2[(size_t)(cbase + i) * CR_ + r8 * 8];  // s_load_dwordx8
                ax[i] = fmaf(wr[0], a0.x, ax[i]);
                ax[i] = fmaf(wr[1], a0.y, ax[i]);
                ax[i] = fmaf(wr[2], a0.z, ax[i]);
                ax[i] = fmaf(wr[3], a0.w, ax[i]);
                ax[i] = fmaf(wr[4], a1.x, ax[i]);
                ax[i] = fmaf(wr[5], a1.y, ax[i]);
                ax[i] = fmaf(wr[6], a1.z, ax[i]);
                ax[i] = fmaf(wr[7], a1.w, ax[i]);
                ay[i] = fmaf(wr[0], c0.x, ay[i]);
                ay[i] = fmaf(wr[1], c0.y, ay[i]);
                ay[i] = fmaf(wr[2], c0.z, ay[i]);
                ay[i] = fmaf(wr[3], c0.w, ay[i]);
                ay[i] = fmaf(wr[4], c1.x, ay[i]);
                ay[i] = fmaf(wr[5], c1.y, ay[i]);
                ay[i] = fmaf(wr[6], c1.z, ay[i]);
                ay[i] = fmaf(wr[7], c1.w, ay[i]);
            }
        }

#pragma unroll
        for (int i = 0; i < 16; ++i) {             // FULL unroll: acc stays in regs
            const int c = cbase + i;
            const float q1  = PQ1[(size_t)c * W_ + h];    // uniform -> s_load
            const float p0x = PQ0[(size_t)c * W_ + w0];
            const float p0y = PQ0[(size_t)c * W_ + w1];
            const float zx = p0x + q1 + 0.495f * ax[i];
            const float zy = p0y + q1 + 0.495f * ay[i];
            const float sgx = 1.0f / (1.0f + __expf(-zx));
            const float sgy = 1.0f / (1.0f + __expf(-zy));
            const size_t xo = ((size_t)(b * C_ + c) * H_ + h) * W_;
            out[xo + w0] = x[xo + w0] * (1.0f + sgx);
            out[xo + w1] = x[xo + w1] * (1.0f + sgy);
        }
    }
}

extern "C" void kernel_launch(void* const* d_in, const int* in_sizes, int n_in,
                              void* d_out, int out_size, void* d_ws, size_t ws_size,
                              hipStream_t stream) {
    (void)in_sizes; (void)n_in; (void)out_size; (void)ws_size;
    const float* x  = (const float*)d_in[0];
    const float* w1 = (const float*)d_in[1];
    const float* w2 = (const float*)d_in[2];
    float* out = (float*)d_out;

    float* S  = (float*)d_ws;              // 4 * 524288 floats
    float* U  = S + 4 * SSTRIDE;           // 4 * 131072 floats
    float* PQ = U + 4 * USTRIDE;           // 2 * 524288 floats
    // total workspace: 3,670,016 floats = 14 MB

    k1_pool<<<dim3(C_, B_), 256, 0, stream>>>(x, S);
    k2a_u  <<<dim3(16, 4, B_), 128, 0, stream>>>(S, w1, U);
    k2b_pq <<<dim3(32, 2, B_), 128, 0, stream>>>(U, w2, PQ);
    k3_gate<<<dim3(H_, B_), 512, 0, stream>>>(x, U, PQ, w2, out);
}